// Round 16
// baseline (669.221 us; speedup 1.0000x reference)
//
#include <hip/hip_runtime.h>
#include <hip/hip_bf16.h>
#include <stdint.h>

#define D 1024
#define N 200000
#define C 50
#define B 4096
#define CLS 4
#define KParts 16
#define CAP 4096
#define BN 256
#define NBLK 782                    // ceil(N/BN); 782*256 = 200192
#define NSLOT (NBLK * 8)            // per-wave key-range slots
#define BLROW 260                   // padded row (u32) of B tile
#define TWORK 784                   // transpose worker blocks
#define NTASK (512 * 49)            // (pair, 4096-col chunk) tasks

typedef __attribute__((ext_vector_type(8))) short short8;
typedef __attribute__((ext_vector_type(4))) float f32x4;

// ws float offsets
static const size_t OFF_U     = 0;                          // C*N uints (keys)
static const size_t OFF_TESQ  = (size_t)C * N;              // N floats
static const size_t OFF_GPART = OFF_TESQ + N;               // KParts*2500
static const size_t OFF_WPART = OFF_GPART + KParts * 2500;  // KParts*200
static const size_t OFF_ABF   = ((OFF_WPART + KParts * 200 + 3) / 4) * 4;  // 65536 ushort
static const size_t OFF_RANGE = OFF_ABF + 32768;            // NSLOT*2 uints
static const size_t OFF_SUMS  = OFF_RANGE + 2 * NSLOT;      // C floats
static const size_t OFF_CNT   = OFF_SUMS + C;               // 1 uint
static const size_t OFF_W8    = ((OFF_CNT + 1 + 3) / 4) * 4; // D*8 floats
static const size_t OFF_PK    = OFF_W8 + (size_t)D * 8;     // NBLK*512*256 u32 (~401MB)

__device__ __forceinline__ unsigned mapf(float v) {
    unsigned u = __float_as_uint(v);
    return (u & 0x80000000u) ? ~u : (u | 0x80000000u);
}
__device__ __forceinline__ float unmapf(unsigned u) {
    unsigned b = (u & 0x80000000u) ? (u ^ 0x80000000u) : ~u;
    return __uint_as_float(b);
}
__device__ __forceinline__ unsigned keyu(float dot, float tesq) {
    return mapf(fmaf(-2.0f, dot, tesq));
}
__device__ __forceinline__ unsigned short f2bf(float f) {   // RNE fp32->bf16
    unsigned u = __float_as_uint(f);
    u += 0x7FFFu + ((u >> 16) & 1u);
    return (unsigned short)(u >> 16);
}

// raw barrier: order LDS only; keep global loads in flight across it
#define TILE_BARRIER() do {                                   \
    asm volatile("s_waitcnt lgkmcnt(0)" ::: "memory");        \
    __builtin_amdgcn_s_barrier();                             \
    asm volatile("" ::: "memory");                            \
} while (0)

// ---------------- Ktrans: gram/wc partials (0..15), A-pack (16), te->bf16 tiled (17..) -------
__global__ __launch_bounds__(256) void ktrans(
    const float* __restrict__ concept, const float* __restrict__ te,
    const float* __restrict__ hxw, float* __restrict__ ws)
{
    int t = threadIdx.x;
    int l = t & 63, w = t >> 6;

    if (blockIdx.x < KParts) {
        __shared__ __align__(16) float ct[64 * 50];
        __shared__ float hs[4 * 64];
        int bid = blockIdx.x;
        int d0 = bid * 64;

        for (int i = t; i < 64 * 50; i += 256) ct[i] = concept[d0 * 50 + i];
        {
            int j = t >> 6, dd = t & 63;
            hs[t] = hxw[j * D + d0 + dd];
        }
        __syncthreads();

        float* gp = ws + OFF_GPART + (size_t)bid * 2500;
        for (int p = t; p < 2500; p += 256) {
            int i = p / 50, j = p - i * 50;
            float acc = 0.f;
            #pragma unroll 8
            for (int dd = 0; dd < 64; ++dd)
                acc = fmaf(ct[dd * 50 + i], ct[dd * 50 + j], acc);
            gp[p] = acc;
        }
        float* wp = ws + OFF_WPART + (size_t)bid * 200;
        if (t < 200) {
            int j = t / 50, c = t - j * 50;
            float acc = 0.f;
            #pragma unroll 8
            for (int dd = 0; dd < 64; ++dd)
                acc = fmaf(hs[j * 64 + dd], ct[dd * 50 + c], acc);
            wp[t] = acc;
        }
        return;
    }

    if (blockIdx.x == KParts) {
        // A-pack: ap[((ks*4+g)*64 + m)*8 + j] = bf16(concept[ks*32+g*8+j][m]), m<50 else 0
        unsigned short* ap = (unsigned short*)(ws + OFF_ABF);
        for (int idx = t; idx < 8192; idx += 256) {
            int ks = idx >> 8;
            int g  = (idx >> 6) & 3;
            int m  = idx & 63;
            unsigned short v[8];
            #pragma unroll
            for (int j = 0; j < 8; ++j) {
                int k = ks * 32 + g * 8 + j;
                v[j] = (m < 50) ? f2bf(concept[k * 50 + m]) : (unsigned short)0;
            }
            uint4 pk;
            pk.x = (unsigned)v[0] | ((unsigned)v[1] << 16);
            pk.y = (unsigned)v[2] | ((unsigned)v[3] << 16);
            pk.z = (unsigned)v[4] | ((unsigned)v[5] << 16);
            pk.w = (unsigned)v[6] | ((unsigned)v[7] << 16);
            *(uint4*)(ap + (size_t)idx * 8) = pk;
        }
        return;
    }

    // ---- transpose worker: task = (chunk j, pair p); reads 2 x 16KB row runs,
    //      writes paired-bf16 1KB bursts into pk[nb][p][256] ----
    unsigned* pkb = (unsigned*)(ws + OFF_PK);
    int gw = (blockIdx.x - (KParts + 1)) * 4 + w;     // 0..3135
    for (int task = gw; task < NTASK; task += TWORK * 4) {
        int j = task / 512;                // col chunk (k-fast order within chunk)
        int p = task - j * 512;            // k-pair
        const float* r0 = te + (size_t)(2 * p) * N;
        const float* r1 = te + (size_t)(2 * p + 1) * N;
        #pragma unroll 4
        for (int q = 0; q < 16; ++q) {
            int c = j * 4096 + q * 256 + l * 4;
            float4 x0, x1;
            if (c < N) {                   // N%4==0 -> quad all-or-nothing
                x0 = *(const float4*)(r0 + c);
                x1 = *(const float4*)(r1 + c);
            } else {
                x0 = make_float4(0.f, 0.f, 0.f, 0.f);
                x1 = make_float4(0.f, 0.f, 0.f, 0.f);
            }
            union { __hip_bfloat162 h; unsigned u; } p0, p1, p2, p3;
            p0.h = __float22bfloat162_rn(make_float2(x0.x, x1.x));
            p1.h = __float22bfloat162_rn(make_float2(x0.y, x1.y));
            p2.h = __float22bfloat162_rn(make_float2(x0.z, x1.z));
            p3.h = __float22bfloat162_rn(make_float2(x0.w, x1.w));
            int nb = j * 16 + q;
            if (nb < NBLK) {
                uint4 pk;
                pk.x = p0.u; pk.y = p1.u; pk.z = p2.u; pk.w = p3.u;
                *(uint4*)(pkb + (size_t)nb * 131072 + (size_t)p * 256 + l * 4) = pk;
            }
        }
    }
}

// ---------------- Kgemm: MFMA dots+keys+tesq (blocks 0..781) | solve (block 782) ----------
__global__ __launch_bounds__(512, 4) void kgemm(
    const float* __restrict__ concept, const float* __restrict__ hxw,
    float* __restrict__ ws, float* __restrict__ out)
{
    __shared__ __align__(16) unsigned char smem[42496];

    int t = threadIdx.x;
    int l = t & 63, w = t >> 6;

    if (blockIdx.x == NBLK) {
        // ---- solve role: gram sum, metrics, pivotless GJ on [G|wc^T], W8 ----
        float* gsh  = (float*)smem;             // 2500
        float* Asv  = (float*)(smem + 10000);   // 50*56
        float* colp = (float*)(smem + 21200);   // 50
        float* part = (float*)(smem + 21408);   // 3*8

        if (t == 0) ((unsigned*)(ws + OFF_CNT))[0] = 0u;

        float s_all = 0.f, s_tr = 0.f, s_abs = 0.f;
        for (int p = t; p < 2500; p += 512) {
            float g = 0.f;
            #pragma unroll
            for (int b = 0; b < KParts; ++b)
                g += ws[OFF_GPART + (size_t)b * 2500 + p];
            gsh[p] = g;
            int i = p / 50, jj = p - i * 50;
            float e = (i == jj) ? 1.0f : 0.0f;
            s_all += g;
            if (i == jj) s_tr += g;
            s_abs += fabsf(g - e);
        }
        #pragma unroll
        for (int off = 32; off > 0; off >>= 1) {
            s_all += __shfl_down(s_all, off, 64);
            s_tr  += __shfl_down(s_tr,  off, 64);
            s_abs += __shfl_down(s_abs, off, 64);
        }
        if (l == 0) { part[0 * 8 + w] = s_all; part[1 * 8 + w] = s_tr; part[2 * 8 + w] = s_abs; }
        __syncthreads();
        if (t == 0) {
            float a = 0.f, tr = 0.f, ab = 0.f;
            for (int i = 0; i < 8; ++i) {
                a += part[0 * 8 + i]; tr += part[1 * 8 + i]; ab += part[2 * 8 + i];
            }
            out[32769] = (a - tr) / 2500.0f;
            out[32770] = tr / 2500.0f;
            out[32771] = ab / 2500.0f;
        }

        for (int p = t; p < 50 * 56; p += 512) {
            int r = p / 56, col = p - r * 56;
            float v = 0.f;
            if (col < 50) v = gsh[r * 50 + col];
            else if (col < 54) {
                float ww = 0.f;
                #pragma unroll
                for (int b = 0; b < KParts; ++b)
                    ww += ws[OFF_WPART + (size_t)b * 200 + (col - 50) * 50 + r];
                v = ww;
            }
            Asv[p] = v;
        }
        __syncthreads();

        for (int pc = 0; pc < C; ++pc) {
            if (t < C) colp[t] = Asv[t * 56 + pc];
            __syncthreads();
            float pinv = 1.0f / colp[pc];
            if (t < 56) Asv[pc * 56 + t] *= pinv;
            __syncthreads();
            for (int p = t; p < 50 * 56; p += 512) {
                int r = p / 56, col = p - r * 56;
                if (r != pc) Asv[p] = fmaf(-colp[r], Asv[pc * 56 + col], Asv[p]);
            }
            __syncthreads();
        }

        for (int d = t; d < D; d += 512) {
            float wy0 = 0.f, wy1 = 0.f, wy2 = 0.f, wy3 = 0.f;
            for (int c = 0; c < C; ++c) {
                float cv = concept[d * 50 + c];
                wy0 = fmaf(cv, Asv[c * 56 + 50], wy0);
                wy1 = fmaf(cv, Asv[c * 56 + 51], wy1);
                wy2 = fmaf(cv, Asv[c * 56 + 52], wy2);
                wy3 = fmaf(cv, Asv[c * 56 + 53], wy3);
            }
            float4 lo, hi;
            lo.x = hxw[0 * D + d]; lo.y = hxw[1 * D + d];
            lo.z = hxw[2 * D + d]; lo.w = hxw[3 * D + d];
            hi.x = wy0; hi.y = wy1; hi.z = wy2; hi.w = wy3;
            *(float4*)(ws + OFF_W8 + (size_t)d * 8)     = lo;
            *(float4*)(ws + OFF_W8 + (size_t)d * 8 + 4) = hi;
        }
        return;
    }

    // ---- GEMM role: B staged from pre-packed tile (sequential 512KB/block) ----
    unsigned* Blb = (unsigned*)smem;                  // [2][16*260]
    float* tsp = (float*)(smem + 33280);              // [8][256]
    float* tsf = (float*)(smem + 33280 + 8192);       // [256]

    int nbase = blockIdx.x * BN;
    int nq = t & 63, rp = w;
    bool colv = true; (void)colv;

    f32x4 accf[2][4];
    #pragma unroll
    for (int mf = 0; mf < 2; ++mf)
        #pragma unroll
        for (int nf = 0; nf < 4; ++nf)
            accf[mf][nf] = (f32x4)(0.0f);
    float ts0 = 0.f, ts1 = 0.f, ts2 = 0.f, ts3 = 0.f;

    const unsigned short* ap = (const unsigned short*)(ws + OFF_ABF);
    const unsigned* pkt = (const unsigned*)(ws + OFF_PK) + (size_t)blockIdx.x * 131072;
    int g = l >> 4;
    int mhalf = w >> 2;
    int nnb = (w & 3) * 64 + (l & 15);

    auto ldtile = [&](int ks, uint4* xr) {
        #pragma unroll
        for (int pi = 0; pi < 2; ++pi) {
            int pair = rp + pi * 8;
            xr[pi] = *(const uint4*)(pkt + (size_t)(ks * 16 + pair) * 256 + nq * 4);
        }
    };

    auto stage_write = [&](int buf, uint4* xr) {
        #pragma unroll
        for (int pi = 0; pi < 2; ++pi) {
            int pair = rp + pi * 8;
            uint4 v = xr[pi];
            float fa0 = __uint_as_float(v.x << 16), fb0 = __uint_as_float(v.x & 0xFFFF0000u);
            float fa1 = __uint_as_float(v.y << 16), fb1 = __uint_as_float(v.y & 0xFFFF0000u);
            float fa2 = __uint_as_float(v.z << 16), fb2 = __uint_as_float(v.z & 0xFFFF0000u);
            float fa3 = __uint_as_float(v.w << 16), fb3 = __uint_as_float(v.w & 0xFFFF0000u);
            ts0 = fmaf(fa0, fa0, fmaf(fb0, fb0, ts0));
            ts1 = fmaf(fa1, fa1, fmaf(fb1, fb1, ts1));
            ts2 = fmaf(fa2, fa2, fmaf(fb2, fb2, ts2));
            ts3 = fmaf(fa3, fa3, fmaf(fb3, fb3, ts3));
            *(uint4*)(&Blb[buf * (16 * BLROW) + pair * BLROW + nq * 4]) = v;
        }
    };

    auto body = [&](int ks, uint4* rload, uint4* rcons) {
        if (ks < 30) ldtile(ks + 2, rload);     // prefetch stays in flight across raw barriers

        short8 af0 = *(const short8*)(ap + ((size_t)(ks * 4 + g) * 64 + mhalf * 32 + 0 * 16 + (l & 15)) * 8);
        short8 af1 = *(const short8*)(ap + ((size_t)(ks * 4 + g) * 64 + mhalf * 32 + 1 * 16 + (l & 15)) * 8);

        const unsigned* Bc = Blb + (ks & 1) * (16 * BLROW);
        #pragma unroll
        for (int nf = 0; nf < 4; ++nf) {
            int nn = nnb + nf * 16;
            union { unsigned u[4]; short8 s; } bu;
            bu.u[0] = Bc[(g * 4 + 0) * BLROW + nn];
            bu.u[1] = Bc[(g * 4 + 1) * BLROW + nn];
            bu.u[2] = Bc[(g * 4 + 2) * BLROW + nn];
            bu.u[3] = Bc[(g * 4 + 3) * BLROW + nn];
            accf[0][nf] = __builtin_amdgcn_mfma_f32_16x16x32_bf16(af0, bu.s, accf[0][nf], 0, 0, 0);
            accf[1][nf] = __builtin_amdgcn_mfma_f32_16x16x32_bf16(af1, bu.s, accf[1][nf], 0, 0, 0);
        }

        if (ks < 31) stage_write((ks + 1) & 1, rcons);
    };

    uint4 r0[2], r1[2];
    ldtile(0, r0);
    ldtile(1, r1);
    stage_write(0, r0);

    #pragma unroll 1
    for (int ks = 0; ks < 32; ks += 2) {
        TILE_BARRIER();
        body(ks, r0, r1);
        TILE_BARRIER();
        body(ks + 1, r1, r0);
    }

    // tesq reduce across the 8 pair-groups
    __syncthreads();
    tsp[rp * 256 + nq * 4 + 0] = ts0;
    tsp[rp * 256 + nq * 4 + 1] = ts1;
    tsp[rp * 256 + nq * 4 + 2] = ts2;
    tsp[rp * 256 + nq * 4 + 3] = ts3;
    __syncthreads();
    if (t < 64) {
        float4 s = make_float4(0.f, 0.f, 0.f, 0.f);
        #pragma unroll
        for (int r = 0; r < 8; ++r) {
            float4 v = *(const float4*)(&tsp[r * 256 + t * 4]);
            s.x += v.x; s.y += v.y; s.z += v.z; s.w += v.w;
        }
        *(float4*)(&tsf[t * 4]) = s;
        if (nbase + t * 4 < N)
            *(float4*)(ws + OFF_TESQ + nbase + t * 4) = s;
    }
    __syncthreads();

    // epilogue: keys + per-wave range
    unsigned* uws = (unsigned*)ws;
    unsigned kmin = 0xFFFFFFFFu, kmax = 0u;
    #pragma unroll
    for (int mf = 0; mf < 2; ++mf) {
        #pragma unroll
        for (int nf = 0; nf < 4; ++nf) {
            int nloc = nnb + nf * 16;
            int nabs = nbase + nloc;
            #pragma unroll
            for (int r = 0; r < 4; ++r) {
                int c = mhalf * 32 + mf * 16 + (l >> 4) * 4 + r;   // C/D row map (m89)
                if (c < 50 && nabs < N) {
                    unsigned u = keyu(accf[mf][nf][r], tsf[nloc]);
                    uws[(size_t)c * N + nabs] = u;
                    kmin = min(kmin, u);
                    kmax = max(kmax, u);
                }
            }
        }
    }
    #pragma unroll
    for (int off = 32; off > 0; off >>= 1) {
        kmin = min(kmin, (unsigned)__shfl_down((int)kmin, off, 64));
        kmax = max(kmax, (unsigned)__shfl_down((int)kmax, off, 64));
    }
    if (l == 0) {
        int slot = blockIdx.x * 8 + w;
        ((unsigned*)(ws + OFF_RANGE))[2 * slot]     = kmin;
        ((unsigned*)(ws + OFF_RANGE))[2 * slot + 1] = kmax;
    }
}

// ---------------- Kpred: [orig_pred | y_pred] = X @ W8 + bias -----------------
__global__ __launch_bounds__(256) void kpred(
    const float* __restrict__ X, const float* __restrict__ hxb,
    const float* __restrict__ ws, float* __restrict__ out)
{
    int t = threadIdx.x;
    int lane = t & 63, w = t >> 6;
    int r = blockIdx.x * 4 + w;
    const float* xr = X + (size_t)r * D;
    const float* w8 = ws + OFF_W8;

    float acc[8];
    #pragma unroll
    for (int j = 0; j < 8; ++j) acc[j] = 0.f;
    #pragma unroll
    for (int i = 0; i < 16; ++i) {
        int d = i * 64 + lane;
        float x = xr[d];
        float4 lo = *(const float4*)(w8 + (size_t)d * 8);
        float4 hi = *(const float4*)(w8 + (size_t)d * 8 + 4);
        acc[0] = fmaf(x, lo.x, acc[0]);
        acc[1] = fmaf(x, lo.y, acc[1]);
        acc[2] = fmaf(x, lo.z, acc[2]);
        acc[3] = fmaf(x, lo.w, acc[3]);
        acc[4] = fmaf(x, hi.x, acc[4]);
        acc[5] = fmaf(x, hi.y, acc[5]);
        acc[6] = fmaf(x, hi.z, acc[6]);
        acc[7] = fmaf(x, hi.w, acc[7]);
    }
    #pragma unroll
    for (int j = 0; j < 8; ++j) {
        float v = acc[j];
        #pragma unroll
        for (int off = 32; off > 0; off >>= 1) v += __shfl_down(v, off, 64);
        if (lane == 0) {
            float b = hxb[j & 3];
            if (j < 4) out[(size_t)r * CLS + j] = v + b;
            else       out[16384 + (size_t)r * CLS + (j - 4)] = v + b;
        }
    }
}

// ---------------- K4: GR preamble + top-k from u keys + fused L_sparse_1 ------
__global__ __launch_bounds__(1024) void k4_select(
    const float* __restrict__ ws, float* __restrict__ wsw,
    float* __restrict__ out, const int* __restrict__ topk)
{
    int c = blockIdx.x, t = threadIdx.x;
    int lane = t & 63, wid = t >> 6;
    const unsigned* uarr = (const unsigned*)ws + (size_t)c * N;
    const float* tesq = ws + OFF_TESQ;

    __shared__ unsigned hist[4096];
    __shared__ unsigned wsum[16], woff[16];
    __shared__ unsigned wmn[16], wmx[16];
    __shared__ unsigned sh_ulo, sh_uhi;
    __shared__ unsigned sh_bin; __shared__ int sh_rem;
    __shared__ int cnt;
    __shared__ unsigned cand_u[CAP];
    __shared__ int      cand_i[CAP];
    __shared__ float fred[16];

    // preamble: global key range from wave slots
    {
        const unsigned* rg = (const unsigned*)(ws + OFF_RANGE);
        unsigned mn = 0xFFFFFFFFu, mx = 0u;
        for (int i = t; i < NSLOT; i += 1024) {
            mn = min(mn, rg[2 * i]);
            mx = max(mx, rg[2 * i + 1]);
        }
        #pragma unroll
        for (int off = 32; off > 0; off >>= 1) {
            mn = min(mn, (unsigned)__shfl_down((int)mn, off, 64));
            mx = max(mx, (unsigned)__shfl_down((int)mx, off, 64));
        }
        if (lane == 0) { wmn[wid] = mn; wmx[wid] = mx; }
        __syncthreads();
        if (t == 0) {
            unsigned m0 = 0xFFFFFFFFu, m1 = 0u;
            for (int w = 0; w < 16; ++w) { m0 = min(m0, wmn[w]); m1 = max(m1, wmx[w]); }
            sh_ulo = m0; sh_uhi = m1;
        }
        __syncthreads();
    }
    unsigned ubase = sh_ulo;
    unsigned ulo = sh_ulo, uhi = sh_uhi;
    int rem = *topk;
    unsigned long long width = (unsigned long long)(uhi - ulo) + 1ull;

    // pass 1: histogram over 4096 linear bins
    for (int i = t; i < 4096; i += 1024) hist[i] = 0u;
    __syncthreads();
    for (int n = t; n < N; n += 1024) {
        unsigned u = uarr[n];
        unsigned bin = (unsigned)(((unsigned long long)(u - ubase) * 4096ull) / width);
        atomicAdd(&hist[bin], 1u);
    }
    __syncthreads();
    {
        unsigned b0 = (unsigned)t * 4u;
        unsigned h0 = hist[b0], h1 = hist[b0 + 1], h2 = hist[b0 + 2], h3 = hist[b0 + 3];
        unsigned s4 = h0 + h1 + h2 + h3;
        unsigned x = s4;
        #pragma unroll
        for (int off = 1; off < 64; off <<= 1) {
            unsigned y = (unsigned)__shfl_up((int)x, off, 64);
            if (lane >= off) x += y;
        }
        if (lane == 63) wsum[wid] = x;
        __syncthreads();
        if (t == 0) {
            unsigned run = 0;
            for (int w = 0; w < 16; ++w) { woff[w] = run; run += wsum[w]; }
        }
        __syncthreads();
        unsigned cumBefore = woff[wid] + x - s4;
        unsigned remu = (unsigned)rem;
        if (cumBefore < remu && remu <= cumBefore + s4) {
            unsigned cum = cumBefore, bin = b0, r2 = 1;
            unsigned hh[4] = {h0, h1, h2, h3};
            #pragma unroll
            for (int j = 0; j < 4; ++j) {
                if (cum + hh[j] >= remu) { bin = b0 + j; r2 = remu - cum; break; }
                cum += hh[j];
            }
            sh_bin = bin; sh_rem = (int)r2;
        }
        __syncthreads();
        unsigned b = sh_bin;
        rem = sh_rem;
        ulo = ubase + (unsigned)(((unsigned long long)b * width + 4095ull) / 4096ull);
        uhi = ubase + (unsigned)((((unsigned long long)(b + 1) * width + 4095ull) / 4096ull) - 1ull);
        __syncthreads();
    }

    // final: sum recovered dots below cutoff bin; collect cutoff-bin candidates
    if (t == 0) cnt = 0;
    __syncthreads();
    float lsum = 0.f;
    for (int n = t; n < N; n += 1024) {
        unsigned u = uarr[n];
        if (u < ulo) {
            lsum += 0.5f * (tesq[n] - unmapf(u));
        } else if (u <= uhi) {
            int s = atomicAdd(&cnt, 1);
            if (s < CAP) { cand_u[s] = u; cand_i[s] = n; }
        }
    }
    __syncthreads();
    int cc = cnt < CAP ? cnt : CAP;
    for (int ci = t; ci < cc; ci += 1024) {
        unsigned ui = cand_u[ci]; int ii = cand_i[ci];
        int rank = 0;
        for (int j = 0; j < cc; ++j) {
            unsigned uj = cand_u[j];
            rank += (uj < ui || (uj == ui && cand_i[j] < ii)) ? 1 : 0;
        }
        if (rank < rem) lsum += 0.5f * (tesq[ii] - unmapf(ui));
    }
    #pragma unroll
    for (int off = 32; off > 0; off >>= 1) lsum += __shfl_down(lsum, off, 64);
    if (lane == 0) fred[wid] = lsum;
    __syncthreads();
    if (t == 0) {
        float tot = 0.f;
        for (int w = 0; w < 16; ++w) tot += fred[w];
        wsw[OFF_SUMS + c] = tot;
        __threadfence();
        unsigned done = atomicAdd((unsigned*)(wsw + OFF_CNT), 1u);
        if (done == C - 1) {
            float s = 0.f;
            for (int i = 0; i < C; ++i) s += atomicAdd(&wsw[OFF_SUMS + i], 0.0f);
            out[32768] = s / (float)((*topk) * C);
        }
    }
}

extern "C" void kernel_launch(void* const* d_in, const int* in_sizes, int n_in,
                              void* d_out, int out_size, void* d_ws, size_t ws_size,
                              hipStream_t stream) {
    (void)in_sizes; (void)n_in; (void)out_size; (void)ws_size;
    const float* concept = (const float*)d_in[0];
    const float* te      = (const float*)d_in[1];
    const float* X       = (const float*)d_in[2];
    const float* hxw     = (const float*)d_in[3];
    const float* hxb     = (const float*)d_in[4];
    const int*   topk    = (const int*)d_in[5];
    float* out = (float*)d_out;
    float* ws  = (float*)d_ws;

    ktrans<<<dim3(KParts + 1 + TWORK), dim3(256), 0, stream>>>(concept, te, hxw, ws);
    kgemm<<<dim3(NBLK + 1), dim3(512), 0, stream>>>(concept, hxw, ws, out);
    kpred<<<dim3(B / 4), dim3(256), 0, stream>>>(X, hxb, ws, out);
    k4_select<<<dim3(C), dim3(1024), 0, stream>>>(ws, ws, out, topk);
}

// Round 17
// 648.488 us; speedup vs baseline: 1.0320x; 1.0320x over previous
//
#include <hip/hip_runtime.h>
#include <hip/hip_bf16.h>
#include <stdint.h>

#define D 1024
#define N 200000
#define C 50
#define B 4096
#define CLS 4
#define KParts 16
#define CAP 4096
#define BN 256
#define NBLK 782                    // ceil(N/BN); 782*256 = 200192
#define NSLOT (NBLK * 8)            // per-wave key-range slots
#define BLROW 260                   // padded row (u32) of B tile
#define TRG 64                      // row groups (16 k-rows = 8 pairs each)
#define TCH 98                      // col chunks of 2048 (98*2048 = 200704)

typedef __attribute__((ext_vector_type(8))) short short8;
typedef __attribute__((ext_vector_type(4))) float f32x4;

// ws float offsets
static const size_t OFF_U     = 0;                          // C*N uints (keys)
static const size_t OFF_TESQ  = (size_t)C * N;              // N floats
static const size_t OFF_GPART = OFF_TESQ + N;               // KParts*2500
static const size_t OFF_WPART = OFF_GPART + KParts * 2500;  // KParts*200
static const size_t OFF_ABF   = ((OFF_WPART + KParts * 200 + 3) / 4) * 4;  // 65536 ushort
static const size_t OFF_RANGE = OFF_ABF + 32768;            // NSLOT*2 uints
static const size_t OFF_SUMS  = OFF_RANGE + 2 * NSLOT;      // C floats
static const size_t OFF_CNT   = OFF_SUMS + C;               // 1 uint
static const size_t OFF_W8    = ((OFF_CNT + 1 + 3) / 4) * 4; // D*8 floats
static const size_t OFF_PK    = OFF_W8 + (size_t)D * 8;     // NBLK*131072 u32 (~401MB)

__device__ __forceinline__ unsigned mapf(float v) {
    unsigned u = __float_as_uint(v);
    return (u & 0x80000000u) ? ~u : (u | 0x80000000u);
}
__device__ __forceinline__ float unmapf(unsigned u) {
    unsigned b = (u & 0x80000000u) ? (u ^ 0x80000000u) : ~u;
    return __uint_as_float(b);
}
__device__ __forceinline__ unsigned keyu(float dot, float tesq) {
    return mapf(fmaf(-2.0f, dot, tesq));
}
__device__ __forceinline__ unsigned short f2bf(float f) {   // RNE fp32->bf16
    unsigned u = __float_as_uint(f);
    u += 0x7FFFu + ((u >> 16) & 1u);
    return (unsigned short)(u >> 16);
}

// raw barrier: order LDS only; keep global loads in flight across it
#define TILE_BARRIER() do {                                   \
    asm volatile("s_waitcnt lgkmcnt(0)" ::: "memory");        \
    __builtin_amdgcn_s_barrier();                             \
    asm volatile("" ::: "memory");                            \
} while (0)

// ---- Ktrans: gram/wc (0..15), A-pack (16), LDS-tiled te transpose w/ 8KB bursts (17..) ----
__global__ __launch_bounds__(256) void ktrans(
    const float* __restrict__ concept, const float* __restrict__ te,
    const float* __restrict__ hxw, float* __restrict__ ws)
{
    __shared__ __align__(16) unsigned char tsm[65536];
    int t = threadIdx.x;

    if (blockIdx.x < KParts) {
        float* ct = (float*)tsm;               // [64*50]
        float* hs = (float*)(tsm + 12800);     // [256]
        int bid = blockIdx.x;
        int d0 = bid * 64;

        for (int i = t; i < 64 * 50; i += 256) ct[i] = concept[d0 * 50 + i];
        {
            int j = t >> 6, dd = t & 63;
            hs[t] = hxw[j * D + d0 + dd];
        }
        __syncthreads();

        float* gp = ws + OFF_GPART + (size_t)bid * 2500;
        for (int p = t; p < 2500; p += 256) {
            int i = p / 50, j = p - i * 50;
            float acc = 0.f;
            #pragma unroll 8
            for (int dd = 0; dd < 64; ++dd)
                acc = fmaf(ct[dd * 50 + i], ct[dd * 50 + j], acc);
            gp[p] = acc;
        }
        float* wp = ws + OFF_WPART + (size_t)bid * 200;
        if (t < 200) {
            int j = t / 50, c = t - j * 50;
            float acc = 0.f;
            #pragma unroll 8
            for (int dd = 0; dd < 64; ++dd)
                acc = fmaf(hs[j * 64 + dd], ct[dd * 50 + c], acc);
            wp[t] = acc;
        }
        return;
    }

    if (blockIdx.x == KParts) {
        unsigned short* ap = (unsigned short*)(ws + OFF_ABF);
        for (int idx = t; idx < 8192; idx += 256) {
            int ks = idx >> 8;
            int g  = (idx >> 6) & 3;
            int m  = idx & 63;
            unsigned short v[8];
            #pragma unroll
            for (int j = 0; j < 8; ++j) {
                int k = ks * 32 + g * 8 + j;
                v[j] = (m < 50) ? f2bf(concept[k * 50 + m]) : (unsigned short)0;
            }
            uint4 pk;
            pk.x = (unsigned)v[0] | ((unsigned)v[1] << 16);
            pk.y = (unsigned)v[2] | ((unsigned)v[3] << 16);
            pk.z = (unsigned)v[4] | ((unsigned)v[5] << 16);
            pk.w = (unsigned)v[6] | ((unsigned)v[7] << 16);
            *(uint4*)(ap + (size_t)idx * 8) = pk;
        }
        return;
    }

    // ---- transpose tile: (rg, ch) = 16 k-rows x 2048 cols ----
    unsigned* lds = (unsigned*)tsm;            // [8 pairs][2048 cols]
    int tb = blockIdx.x - (KParts + 1);        // 0..TRG*TCH-1
    int rg = tb % TRG, ch = tb / TRG;
    int k0 = rg * 16;
    size_t base = (size_t)ch * 2048;

    // read phase: 8KB sequential runs per row, convert+pair into LDS
    #pragma unroll 2
    for (int it = 0; it < 16; ++it) {
        int idx = it * 256 + t;
        int pp = idx >> 9;                     // pair-in-group 0..7
        int cq = idx & 511;                    // col quad 0..511
        size_t c = base + (size_t)cq * 4;
        float4 x0, x1;
        if (c < (size_t)N) {
            x0 = *(const float4*)(te + (size_t)(k0 + 2 * pp) * N + c);
            x1 = *(const float4*)(te + (size_t)(k0 + 2 * pp + 1) * N + c);
        } else {
            x0 = make_float4(0.f, 0.f, 0.f, 0.f);
            x1 = make_float4(0.f, 0.f, 0.f, 0.f);
        }
        union { __hip_bfloat162 h; unsigned u; } p0, p1, p2, p3;
        p0.h = __float22bfloat162_rn(make_float2(x0.x, x1.x));
        p1.h = __float22bfloat162_rn(make_float2(x0.y, x1.y));
        p2.h = __float22bfloat162_rn(make_float2(x0.z, x1.z));
        p3.h = __float22bfloat162_rn(make_float2(x0.w, x1.w));
        uint4 pk;
        pk.x = p0.u; pk.y = p1.u; pk.z = p2.u; pk.w = p3.u;
        *(uint4*)(lds + pp * 2048 + cq * 4) = pk;
    }
    __syncthreads();

    // write phase: 8KB contiguous per (nb, rg) region
    unsigned* pkb = (unsigned*)(ws + OFF_PK);
    #pragma unroll 2
    for (int it = 0; it < 16; ++it) {
        int idx = it * 256 + t;
        int q  = idx >> 9;                     // sub-tile 0..7 (nb = ch*8+q)
        int wq = idx & 511;                    // u32-quad within 8KB
        int nb = ch * 8 + q;
        if (nb < NBLK) {
            int g = wq * 4;
            int p = g >> 8;                    // pair-in-group
            int col = g & 255;
            uint4 v = *(const uint4*)(lds + p * 2048 + q * 256 + col);
            *(uint4*)(pkb + (size_t)nb * 131072 + (size_t)(rg * 8) * 256 + g) = v;
        }
    }
}

// ---------------- Kgemm: MFMA dots+keys+tesq (blocks 0..781) | solve (block 782) ----------
__global__ __launch_bounds__(512, 4) void kgemm(
    const float* __restrict__ concept, const float* __restrict__ hxw,
    float* __restrict__ ws, float* __restrict__ out)
{
    __shared__ __align__(16) unsigned char smem[42496];

    int t = threadIdx.x;
    int l = t & 63, w = t >> 6;

    if (blockIdx.x == NBLK) {
        // ---- solve role ----
        float* gsh  = (float*)smem;             // 2500
        float* Asv  = (float*)(smem + 10000);   // 50*56
        float* colp = (float*)(smem + 21200);   // 50
        float* part = (float*)(smem + 21408);   // 3*8

        if (t == 0) ((unsigned*)(ws + OFF_CNT))[0] = 0u;

        float s_all = 0.f, s_tr = 0.f, s_abs = 0.f;
        for (int p = t; p < 2500; p += 512) {
            float g = 0.f;
            #pragma unroll
            for (int b = 0; b < KParts; ++b)
                g += ws[OFF_GPART + (size_t)b * 2500 + p];
            gsh[p] = g;
            int i = p / 50, jj = p - i * 50;
            float e = (i == jj) ? 1.0f : 0.0f;
            s_all += g;
            if (i == jj) s_tr += g;
            s_abs += fabsf(g - e);
        }
        #pragma unroll
        for (int off = 32; off > 0; off >>= 1) {
            s_all += __shfl_down(s_all, off, 64);
            s_tr  += __shfl_down(s_tr,  off, 64);
            s_abs += __shfl_down(s_abs, off, 64);
        }
        if (l == 0) { part[0 * 8 + w] = s_all; part[1 * 8 + w] = s_tr; part[2 * 8 + w] = s_abs; }
        __syncthreads();
        if (t == 0) {
            float a = 0.f, tr = 0.f, ab = 0.f;
            for (int i = 0; i < 8; ++i) {
                a += part[0 * 8 + i]; tr += part[1 * 8 + i]; ab += part[2 * 8 + i];
            }
            out[32769] = (a - tr) / 2500.0f;
            out[32770] = tr / 2500.0f;
            out[32771] = ab / 2500.0f;
        }

        for (int p = t; p < 50 * 56; p += 512) {
            int r = p / 56, col = p - r * 56;
            float v = 0.f;
            if (col < 50) v = gsh[r * 50 + col];
            else if (col < 54) {
                float ww = 0.f;
                #pragma unroll
                for (int b = 0; b < KParts; ++b)
                    ww += ws[OFF_WPART + (size_t)b * 200 + (col - 50) * 50 + r];
                v = ww;
            }
            Asv[p] = v;
        }
        __syncthreads();

        for (int pc = 0; pc < C; ++pc) {
            if (t < C) colp[t] = Asv[t * 56 + pc];
            __syncthreads();
            float pinv = 1.0f / colp[pc];
            if (t < 56) Asv[pc * 56 + t] *= pinv;
            __syncthreads();
            for (int p = t; p < 50 * 56; p += 512) {
                int r = p / 56, col = p - r * 56;
                if (r != pc) Asv[p] = fmaf(-colp[r], Asv[pc * 56 + col], Asv[p]);
            }
            __syncthreads();
        }

        for (int d = t; d < D; d += 512) {
            float wy0 = 0.f, wy1 = 0.f, wy2 = 0.f, wy3 = 0.f;
            for (int c = 0; c < C; ++c) {
                float cv = concept[d * 50 + c];
                wy0 = fmaf(cv, Asv[c * 56 + 50], wy0);
                wy1 = fmaf(cv, Asv[c * 56 + 51], wy1);
                wy2 = fmaf(cv, Asv[c * 56 + 52], wy2);
                wy3 = fmaf(cv, Asv[c * 56 + 53], wy3);
            }
            float4 lo, hi;
            lo.x = hxw[0 * D + d]; lo.y = hxw[1 * D + d];
            lo.z = hxw[2 * D + d]; lo.w = hxw[3 * D + d];
            hi.x = wy0; hi.y = wy1; hi.z = wy2; hi.w = wy3;
            *(float4*)(ws + OFF_W8 + (size_t)d * 8)     = lo;
            *(float4*)(ws + OFF_W8 + (size_t)d * 8 + 4) = hi;
        }
        return;
    }

    // ---- GEMM role: B staged from pre-packed tile (sequential 512KB/block) ----
    unsigned* Blb = (unsigned*)smem;                  // [2][16*260]
    float* tsp = (float*)(smem + 33280);              // [8][256]
    float* tsf = (float*)(smem + 33280 + 8192);       // [256]

    int nbase = blockIdx.x * BN;
    int nq = t & 63, rp = w;

    f32x4 accf[2][4];
    #pragma unroll
    for (int mf = 0; mf < 2; ++mf)
        #pragma unroll
        for (int nf = 0; nf < 4; ++nf)
            accf[mf][nf] = (f32x4)(0.0f);
    float ts0 = 0.f, ts1 = 0.f, ts2 = 0.f, ts3 = 0.f;

    const unsigned short* ap = (const unsigned short*)(ws + OFF_ABF);
    const unsigned* pkt = (const unsigned*)(ws + OFF_PK) + (size_t)blockIdx.x * 131072;
    int g = l >> 4;
    int mhalf = w >> 2;
    int nnb = (w & 3) * 64 + (l & 15);

    auto ldtile = [&](int ks, uint4* xr) {
        #pragma unroll
        for (int pi = 0; pi < 2; ++pi) {
            int pair = rp + pi * 8;
            xr[pi] = *(const uint4*)(pkt + (size_t)(ks * 16 + pair) * 256 + nq * 4);
        }
    };

    auto stage_write = [&](int buf, uint4* xr) {
        #pragma unroll
        for (int pi = 0; pi < 2; ++pi) {
            int pair = rp + pi * 8;
            uint4 v = xr[pi];
            float fa0 = __uint_as_float(v.x << 16), fb0 = __uint_as_float(v.x & 0xFFFF0000u);
            float fa1 = __uint_as_float(v.y << 16), fb1 = __uint_as_float(v.y & 0xFFFF0000u);
            float fa2 = __uint_as_float(v.z << 16), fb2 = __uint_as_float(v.z & 0xFFFF0000u);
            float fa3 = __uint_as_float(v.w << 16), fb3 = __uint_as_float(v.w & 0xFFFF0000u);
            ts0 = fmaf(fa0, fa0, fmaf(fb0, fb0, ts0));
            ts1 = fmaf(fa1, fa1, fmaf(fb1, fb1, ts1));
            ts2 = fmaf(fa2, fa2, fmaf(fb2, fb2, ts2));
            ts3 = fmaf(fa3, fa3, fmaf(fb3, fb3, ts3));
            *(uint4*)(&Blb[buf * (16 * BLROW) + pair * BLROW + nq * 4]) = v;
        }
    };

    auto body = [&](int ks, uint4* rload, uint4* rcons) {
        if (ks < 30) ldtile(ks + 2, rload);

        short8 af0 = *(const short8*)(ap + ((size_t)(ks * 4 + g) * 64 + mhalf * 32 + 0 * 16 + (l & 15)) * 8);
        short8 af1 = *(const short8*)(ap + ((size_t)(ks * 4 + g) * 64 + mhalf * 32 + 1 * 16 + (l & 15)) * 8);

        const unsigned* Bc = Blb + (ks & 1) * (16 * BLROW);
        #pragma unroll
        for (int nf = 0; nf < 4; ++nf) {
            int nn = nnb + nf * 16;
            union { unsigned u[4]; short8 s; } bu;
            bu.u[0] = Bc[(g * 4 + 0) * BLROW + nn];
            bu.u[1] = Bc[(g * 4 + 1) * BLROW + nn];
            bu.u[2] = Bc[(g * 4 + 2) * BLROW + nn];
            bu.u[3] = Bc[(g * 4 + 3) * BLROW + nn];
            accf[0][nf] = __builtin_amdgcn_mfma_f32_16x16x32_bf16(af0, bu.s, accf[0][nf], 0, 0, 0);
            accf[1][nf] = __builtin_amdgcn_mfma_f32_16x16x32_bf16(af1, bu.s, accf[1][nf], 0, 0, 0);
        }

        if (ks < 31) stage_write((ks + 1) & 1, rcons);
    };

    uint4 r0[2], r1[2];
    ldtile(0, r0);
    ldtile(1, r1);
    stage_write(0, r0);

    #pragma unroll 1
    for (int ks = 0; ks < 32; ks += 2) {
        TILE_BARRIER();
        body(ks, r0, r1);
        TILE_BARRIER();
        body(ks + 1, r1, r0);
    }

    __syncthreads();
    tsp[rp * 256 + nq * 4 + 0] = ts0;
    tsp[rp * 256 + nq * 4 + 1] = ts1;
    tsp[rp * 256 + nq * 4 + 2] = ts2;
    tsp[rp * 256 + nq * 4 + 3] = ts3;
    __syncthreads();
    if (t < 64) {
        float4 s = make_float4(0.f, 0.f, 0.f, 0.f);
        #pragma unroll
        for (int r = 0; r < 8; ++r) {
            float4 v = *(const float4*)(&tsp[r * 256 + t * 4]);
            s.x += v.x; s.y += v.y; s.z += v.z; s.w += v.w;
        }
        *(float4*)(&tsf[t * 4]) = s;
        if (nbase + t * 4 < N)
            *(float4*)(ws + OFF_TESQ + nbase + t * 4) = s;
    }
    __syncthreads();

    unsigned* uws = (unsigned*)ws;
    unsigned kmin = 0xFFFFFFFFu, kmax = 0u;
    #pragma unroll
    for (int mf = 0; mf < 2; ++mf) {
        #pragma unroll
        for (int nf = 0; nf < 4; ++nf) {
            int nloc = nnb + nf * 16;
            int nabs = nbase + nloc;
            #pragma unroll
            for (int r = 0; r < 4; ++r) {
                int c = mhalf * 32 + mf * 16 + (l >> 4) * 4 + r;   // C/D row map (m89)
                if (c < 50 && nabs < N) {
                    unsigned u = keyu(accf[mf][nf][r], tsf[nloc]);
                    uws[(size_t)c * N + nabs] = u;
                    kmin = min(kmin, u);
                    kmax = max(kmax, u);
                }
            }
        }
    }
    #pragma unroll
    for (int off = 32; off > 0; off >>= 1) {
        kmin = min(kmin, (unsigned)__shfl_down((int)kmin, off, 64));
        kmax = max(kmax, (unsigned)__shfl_down((int)kmax, off, 64));
    }
    if (l == 0) {
        int slot = blockIdx.x * 8 + w;
        ((unsigned*)(ws + OFF_RANGE))[2 * slot]     = kmin;
        ((unsigned*)(ws + OFF_RANGE))[2 * slot + 1] = kmax;
    }
}

// ---------------- Kpred: [orig_pred | y_pred] = X @ W8 + bias -----------------
__global__ __launch_bounds__(256) void kpred(
    const float* __restrict__ X, const float* __restrict__ hxb,
    const float* __restrict__ ws, float* __restrict__ out)
{
    int t = threadIdx.x;
    int lane = t & 63, w = t >> 6;
    int r = blockIdx.x * 4 + w;
    const float* xr = X + (size_t)r * D;
    const float* w8 = ws + OFF_W8;

    float acc[8];
    #pragma unroll
    for (int j = 0; j < 8; ++j) acc[j] = 0.f;
    #pragma unroll
    for (int i = 0; i < 16; ++i) {
        int d = i * 64 + lane;
        float x = xr[d];
        float4 lo = *(const float4*)(w8 + (size_t)d * 8);
        float4 hi = *(const float4*)(w8 + (size_t)d * 8 + 4);
        acc[0] = fmaf(x, lo.x, acc[0]);
        acc[1] = fmaf(x, lo.y, acc[1]);
        acc[2] = fmaf(x, lo.z, acc[2]);
        acc[3] = fmaf(x, lo.w, acc[3]);
        acc[4] = fmaf(x, hi.x, acc[4]);
        acc[5] = fmaf(x, hi.y, acc[5]);
        acc[6] = fmaf(x, hi.z, acc[6]);
        acc[7] = fmaf(x, hi.w, acc[7]);
    }
    #pragma unroll
    for (int j = 0; j < 8; ++j) {
        float v = acc[j];
        #pragma unroll
        for (int off = 32; off > 0; off >>= 1) v += __shfl_down(v, off, 64);
        if (lane == 0) {
            float b = hxb[j & 3];
            if (j < 4) out[(size_t)r * CLS + j] = v + b;
            else       out[16384 + (size_t)r * CLS + (j - 4)] = v + b;
        }
    }
}

// ---------------- K4: GR preamble + top-k from u keys + fused L_sparse_1 ------
__global__ __launch_bounds__(1024) void k4_select(
    const float* __restrict__ ws, float* __restrict__ wsw,
    float* __restrict__ out, const int* __restrict__ topk)
{
    int c = blockIdx.x, t = threadIdx.x;
    int lane = t & 63, wid = t >> 6;
    const unsigned* uarr = (const unsigned*)ws + (size_t)c * N;
    const float* tesq = ws + OFF_TESQ;

    __shared__ unsigned hist[4096];
    __shared__ unsigned wsum[16], woff[16];
    __shared__ unsigned wmn[16], wmx[16];
    __shared__ unsigned sh_ulo, sh_uhi;
    __shared__ unsigned sh_bin; __shared__ int sh_rem;
    __shared__ int cnt;
    __shared__ unsigned cand_u[CAP];
    __shared__ int      cand_i[CAP];
    __shared__ float fred[16];

    {
        const unsigned* rg = (const unsigned*)(ws + OFF_RANGE);
        unsigned mn = 0xFFFFFFFFu, mx = 0u;
        for (int i = t; i < NSLOT; i += 1024) {
            mn = min(mn, rg[2 * i]);
            mx = max(mx, rg[2 * i + 1]);
        }
        #pragma unroll
        for (int off = 32; off > 0; off >>= 1) {
            mn = min(mn, (unsigned)__shfl_down((int)mn, off, 64));
            mx = max(mx, (unsigned)__shfl_down((int)mx, off, 64));
        }
        if (lane == 0) { wmn[wid] = mn; wmx[wid] = mx; }
        __syncthreads();
        if (t == 0) {
            unsigned m0 = 0xFFFFFFFFu, m1 = 0u;
            for (int w = 0; w < 16; ++w) { m0 = min(m0, wmn[w]); m1 = max(m1, wmx[w]); }
            sh_ulo = m0; sh_uhi = m1;
        }
        __syncthreads();
    }
    unsigned ubase = sh_ulo;
    unsigned ulo = sh_ulo, uhi = sh_uhi;
    int rem = *topk;
    unsigned long long width = (unsigned long long)(uhi - ulo) + 1ull;

    for (int i = t; i < 4096; i += 1024) hist[i] = 0u;
    __syncthreads();
    for (int n = t; n < N; n += 1024) {
        unsigned u = uarr[n];
        unsigned bin = (unsigned)(((unsigned long long)(u - ubase) * 4096ull) / width);
        atomicAdd(&hist[bin], 1u);
    }
    __syncthreads();
    {
        unsigned b0 = (unsigned)t * 4u;
        unsigned h0 = hist[b0], h1 = hist[b0 + 1], h2 = hist[b0 + 2], h3 = hist[b0 + 3];
        unsigned s4 = h0 + h1 + h2 + h3;
        unsigned x = s4;
        #pragma unroll
        for (int off = 1; off < 64; off <<= 1) {
            unsigned y = (unsigned)__shfl_up((int)x, off, 64);
            if (lane >= off) x += y;
        }
        if (lane == 63) wsum[wid] = x;
        __syncthreads();
        if (t == 0) {
            unsigned run = 0;
            for (int w = 0; w < 16; ++w) { woff[w] = run; run += wsum[w]; }
        }
        __syncthreads();
        unsigned cumBefore = woff[wid] + x - s4;
        unsigned remu = (unsigned)rem;
        if (cumBefore < remu && remu <= cumBefore + s4) {
            unsigned cum = cumBefore, bin = b0, r2 = 1;
            unsigned hh[4] = {h0, h1, h2, h3};
            #pragma unroll
            for (int j = 0; j < 4; ++j) {
                if (cum + hh[j] >= remu) { bin = b0 + j; r2 = remu - cum; break; }
                cum += hh[j];
            }
            sh_bin = bin; sh_rem = (int)r2;
        }
        __syncthreads();
        unsigned b = sh_bin;
        rem = sh_rem;
        ulo = ubase + (unsigned)(((unsigned long long)b * width + 4095ull) / 4096ull);
        uhi = ubase + (unsigned)((((unsigned long long)(b + 1) * width + 4095ull) / 4096ull) - 1ull);
        __syncthreads();
    }

    if (t == 0) cnt = 0;
    __syncthreads();
    float lsum = 0.f;
    for (int n = t; n < N; n += 1024) {
        unsigned u = uarr[n];
        if (u < ulo) {
            lsum += 0.5f * (tesq[n] - unmapf(u));
        } else if (u <= uhi) {
            int s = atomicAdd(&cnt, 1);
            if (s < CAP) { cand_u[s] = u; cand_i[s] = n; }
        }
    }
    __syncthreads();
    int cc = cnt < CAP ? cnt : CAP;
    for (int ci = t; ci < cc; ci += 1024) {
        unsigned ui = cand_u[ci]; int ii = cand_i[ci];
        int rank = 0;
        for (int j = 0; j < cc; ++j) {
            unsigned uj = cand_u[j];
            rank += (uj < ui || (uj == ui && cand_i[j] < ii)) ? 1 : 0;
        }
        if (rank < rem) lsum += 0.5f * (tesq[ii] - unmapf(ui));
    }
    #pragma unroll
    for (int off = 32; off > 0; off >>= 1) lsum += __shfl_down(lsum, off, 64);
    if (lane == 0) fred[wid] = lsum;
    __syncthreads();
    if (t == 0) {
        float tot = 0.f;
        for (int w = 0; w < 16; ++w) tot += fred[w];
        wsw[OFF_SUMS + c] = tot;
        __threadfence();
        unsigned done = atomicAdd((unsigned*)(wsw + OFF_CNT), 1u);
        if (done == C - 1) {
            float s = 0.f;
            for (int i = 0; i < C; ++i) s += atomicAdd(&wsw[OFF_SUMS + i], 0.0f);
            out[32768] = s / (float)((*topk) * C);
        }
    }
}

extern "C" void kernel_launch(void* const* d_in, const int* in_sizes, int n_in,
                              void* d_out, int out_size, void* d_ws, size_t ws_size,
                              hipStream_t stream) {
    (void)in_sizes; (void)n_in; (void)out_size; (void)ws_size;
    const float* concept = (const float*)d_in[0];
    const float* te      = (const float*)d_in[1];
    const float* X       = (const float*)d_in[2];
    const float* hxw     = (const float*)d_in[3];
    const float* hxb     = (const float*)d_in[4];
    const int*   topk    = (const int*)d_in[5];
    float* out = (float*)d_out;
    float* ws  = (float*)d_ws;

    ktrans<<<dim3(KParts + 1 + TRG * TCH), dim3(256), 0, stream>>>(concept, te, hxw, ws);
    kgemm<<<dim3(NBLK + 1), dim3(512), 0, stream>>>(concept, hxw, ws, out);
    kpred<<<dim3(B / 4), dim3(256), 0, stream>>>(X, hxb, ws, out);
    k4_select<<<dim3(C), dim3(1024), 0, stream>>>(ws, ws, out, topk);
}

// Round 18
// 508.250 us; speedup vs baseline: 1.3167x; 1.2759x over previous
//
#include <hip/hip_runtime.h>
#include <hip/hip_bf16.h>
#include <stdint.h>

#define D 1024
#define N 200000
#define C 50
#define B 4096
#define CLS 4
#define KParts 16
#define CAP 4096
#define BN 256
#define NBLK 782                    // ceil(N/BN); 782*256 = 200192
#define NSLOT (NBLK * 8)            // per-wave key-range slots
#define BLROW 260                   // padded row (u32) of B tile

typedef __attribute__((ext_vector_type(8))) short short8;
typedef __attribute__((ext_vector_type(4))) float f32x4;

// ws float offsets
static const size_t OFF_U     = 0;                          // C*N uints (keys)
static const size_t OFF_TESQ  = (size_t)C * N;              // N floats
static const size_t OFF_GPART = OFF_TESQ + N;               // KParts*2500
static const size_t OFF_WPART = OFF_GPART + KParts * 2500;  // KParts*200
static const size_t OFF_ABF   = ((OFF_WPART + KParts * 200 + 3) / 4) * 4;  // 65536 ushort
static const size_t OFF_RANGE = OFF_ABF + 32768;            // NSLOT*2 uints
static const size_t OFF_SUMS  = OFF_RANGE + 2 * NSLOT;      // C floats
static const size_t OFF_CNT   = OFF_SUMS + C;               // 1 uint
static const size_t OFF_W8    = ((OFF_CNT + 1 + 3) / 4) * 4; // D*8 floats

__device__ __forceinline__ unsigned mapf(float v) {
    unsigned u = __float_as_uint(v);
    return (u & 0x80000000u) ? ~u : (u | 0x80000000u);
}
__device__ __forceinline__ float unmapf(unsigned u) {
    unsigned b = (u & 0x80000000u) ? (u ^ 0x80000000u) : ~u;
    return __uint_as_float(b);
}
__device__ __forceinline__ unsigned keyu(float dot, float tesq) {
    return mapf(fmaf(-2.0f, dot, tesq));
}
__device__ __forceinline__ unsigned short f2bf(float f) {   // RNE fp32->bf16
    unsigned u = __float_as_uint(f);
    u += 0x7FFFu + ((u >> 16) & 1u);
    return (unsigned short)(u >> 16);
}

// raw barrier: order LDS only; keep global loads in flight across it
#define TILE_BARRIER() do {                                   \
    asm volatile("s_waitcnt lgkmcnt(0)" ::: "memory");        \
    __builtin_amdgcn_s_barrier();                             \
    asm volatile("" ::: "memory");                            \
} while (0)

// ---------------- Kprep: gram/wc partials (blocks 0..15) + A-bf16 pack (block 16) ----------
__global__ __launch_bounds__(256) void kprep(
    const float* __restrict__ concept, const float* __restrict__ hxw,
    float* __restrict__ ws)
{
    int t = threadIdx.x;

    if (blockIdx.x < KParts) {
        __shared__ __align__(16) float ct[64 * 50];
        __shared__ float hs[4 * 64];
        int bid = blockIdx.x;
        int d0 = bid * 64;

        for (int i = t; i < 64 * 50; i += 256) ct[i] = concept[d0 * 50 + i];
        {
            int j = t >> 6, dd = t & 63;
            hs[t] = hxw[j * D + d0 + dd];
        }
        __syncthreads();

        float* gp = ws + OFF_GPART + (size_t)bid * 2500;
        for (int p = t; p < 2500; p += 256) {
            int i = p / 50, j = p - i * 50;
            float acc = 0.f;
            #pragma unroll 8
            for (int dd = 0; dd < 64; ++dd)
                acc = fmaf(ct[dd * 50 + i], ct[dd * 50 + j], acc);
            gp[p] = acc;
        }
        float* wp = ws + OFF_WPART + (size_t)bid * 200;
        if (t < 200) {
            int j = t / 50, c = t - j * 50;
            float acc = 0.f;
            #pragma unroll 8
            for (int dd = 0; dd < 64; ++dd)
                acc = fmaf(hs[j * 64 + dd], ct[dd * 50 + c], acc);
            wp[t] = acc;
        }
        return;
    }

    // A-pack: ap[((ks*4+g)*64 + m)*8 + j] = bf16(concept[ks*32+g*8+j][m]), m<50 else 0
    unsigned short* ap = (unsigned short*)(ws + OFF_ABF);
    for (int idx = t; idx < 8192; idx += 256) {
        int ks = idx >> 8;
        int g  = (idx >> 6) & 3;
        int m  = idx & 63;
        unsigned short v[8];
        #pragma unroll
        for (int j = 0; j < 8; ++j) {
            int k = ks * 32 + g * 8 + j;
            v[j] = (m < 50) ? f2bf(concept[k * 50 + m]) : (unsigned short)0;
        }
        uint4 pk;
        pk.x = (unsigned)v[0] | ((unsigned)v[1] << 16);
        pk.y = (unsigned)v[2] | ((unsigned)v[3] << 16);
        pk.z = (unsigned)v[4] | ((unsigned)v[5] << 16);
        pk.w = (unsigned)v[6] | ((unsigned)v[7] << 16);
        *(uint4*)(ap + (size_t)idx * 8) = pk;
    }
}

// ---------------- Kgemm: MFMA dots+keys+tesq (blocks 0..781) | solve (block 782) ----------
__global__ __launch_bounds__(512, 4) void kgemm(
    const float* __restrict__ concept, const float* __restrict__ te,
    const float* __restrict__ hxw, float* __restrict__ ws,
    float* __restrict__ out)
{
    __shared__ __align__(16) unsigned char smem[42496];

    int t = threadIdx.x;
    int l = t & 63, w = t >> 6;

    if (blockIdx.x == NBLK) {
        // ---- solve role: gram sum, metrics, pivotless GJ on [G|wc^T], W8 ----
        float* gsh  = (float*)smem;             // 2500
        float* Asv  = (float*)(smem + 10000);   // 50*56
        float* colp = (float*)(smem + 21200);   // 50
        float* part = (float*)(smem + 21408);   // 3*8

        if (t == 0) ((unsigned*)(ws + OFF_CNT))[0] = 0u;

        float s_all = 0.f, s_tr = 0.f, s_abs = 0.f;
        for (int p = t; p < 2500; p += 512) {
            float g = 0.f;
            #pragma unroll
            for (int b = 0; b < KParts; ++b)
                g += ws[OFF_GPART + (size_t)b * 2500 + p];
            gsh[p] = g;
            int i = p / 50, jj = p - i * 50;
            float e = (i == jj) ? 1.0f : 0.0f;
            s_all += g;
            if (i == jj) s_tr += g;
            s_abs += fabsf(g - e);
        }
        #pragma unroll
        for (int off = 32; off > 0; off >>= 1) {
            s_all += __shfl_down(s_all, off, 64);
            s_tr  += __shfl_down(s_tr,  off, 64);
            s_abs += __shfl_down(s_abs, off, 64);
        }
        if (l == 0) { part[0 * 8 + w] = s_all; part[1 * 8 + w] = s_tr; part[2 * 8 + w] = s_abs; }
        __syncthreads();
        if (t == 0) {
            float a = 0.f, tr = 0.f, ab = 0.f;
            for (int i = 0; i < 8; ++i) {
                a += part[0 * 8 + i]; tr += part[1 * 8 + i]; ab += part[2 * 8 + i];
            }
            out[32769] = (a - tr) / 2500.0f;
            out[32770] = tr / 2500.0f;
            out[32771] = ab / 2500.0f;
        }

        for (int p = t; p < 50 * 56; p += 512) {
            int r = p / 56, col = p - r * 56;
            float v = 0.f;
            if (col < 50) v = gsh[r * 50 + col];
            else if (col < 54) {
                float ww = 0.f;
                #pragma unroll
                for (int b = 0; b < KParts; ++b)
                    ww += ws[OFF_WPART + (size_t)b * 200 + (col - 50) * 50 + r];
                v = ww;
            }
            Asv[p] = v;
        }
        __syncthreads();

        for (int pc = 0; pc < C; ++pc) {
            if (t < C) colp[t] = Asv[t * 56 + pc];
            __syncthreads();
            float pinv = 1.0f / colp[pc];
            if (t < 56) Asv[pc * 56 + t] *= pinv;
            __syncthreads();
            for (int p = t; p < 50 * 56; p += 512) {
                int r = p / 56, col = p - r * 56;
                if (r != pc) Asv[p] = fmaf(-colp[r], Asv[pc * 56 + col], Asv[p]);
            }
            __syncthreads();
        }

        for (int d = t; d < D; d += 512) {
            float wy0 = 0.f, wy1 = 0.f, wy2 = 0.f, wy3 = 0.f;
            for (int c = 0; c < C; ++c) {
                float cv = concept[d * 50 + c];
                wy0 = fmaf(cv, Asv[c * 56 + 50], wy0);
                wy1 = fmaf(cv, Asv[c * 56 + 51], wy1);
                wy2 = fmaf(cv, Asv[c * 56 + 52], wy2);
                wy3 = fmaf(cv, Asv[c * 56 + 53], wy3);
            }
            float4 lo, hi;
            lo.x = hxw[0 * D + d]; lo.y = hxw[1 * D + d];
            lo.z = hxw[2 * D + d]; lo.w = hxw[3 * D + d];
            hi.x = wy0; hi.y = wy1; hi.z = wy2; hi.w = wy3;
            *(float4*)(ws + OFF_W8 + (size_t)d * 8)     = lo;
            *(float4*)(ws + OFF_W8 + (size_t)d * 8 + 4) = hi;
        }
        return;
    }

    // ---- GEMM role ----
    unsigned* Blb = (unsigned*)smem;                  // [2][16*260]
    float* tsp = (float*)(smem + 33280);              // [8][256]
    float* tsf = (float*)(smem + 33280 + 8192);       // [256]

    int nbase = blockIdx.x * BN;
    int nq = t & 63, rp = w;
    int ncol0 = nbase + nq * 4;
    bool colv = (ncol0 < N);

    f32x4 accf[2][4];
    #pragma unroll
    for (int mf = 0; mf < 2; ++mf)
        #pragma unroll
        for (int nf = 0; nf < 4; ++nf)
            accf[mf][nf] = (f32x4)(0.0f);
    float ts0 = 0.f, ts1 = 0.f, ts2 = 0.f, ts3 = 0.f;

    const unsigned short* ap = (const unsigned short*)(ws + OFF_ABF);
    int g = l >> 4;
    int mhalf = w >> 2;
    int nnb = (w & 3) * 64 + (l & 15);

    auto ldtile = [&](int ks, float4* xr) {
        #pragma unroll
        for (int pi = 0; pi < 2; ++pi) {
            int pair = rp + pi * 8;
            int k0 = ks * 32 + pair * 2;
            if (colv) {
                xr[2 * pi]     = *(const float4*)(te + (size_t)k0 * N + ncol0);
                xr[2 * pi + 1] = *(const float4*)(te + (size_t)(k0 + 1) * N + ncol0);
            } else {
                xr[2 * pi]     = make_float4(0.f, 0.f, 0.f, 0.f);
                xr[2 * pi + 1] = make_float4(0.f, 0.f, 0.f, 0.f);
            }
        }
    };

    auto cvt_write = [&](int buf, float4* xr) {
        #pragma unroll
        for (int pi = 0; pi < 2; ++pi) {
            int pair = rp + pi * 8;
            float4 xa = xr[2 * pi], xb = xr[2 * pi + 1];
            union { __hip_bfloat162 h; unsigned u; } p0, p1, p2, p3;
            p0.h = __float22bfloat162_rn(make_float2(xa.x, xb.x));
            p1.h = __float22bfloat162_rn(make_float2(xa.y, xb.y));
            p2.h = __float22bfloat162_rn(make_float2(xa.z, xb.z));
            p3.h = __float22bfloat162_rn(make_float2(xa.w, xb.w));
            float fa0 = __uint_as_float(p0.u << 16), fb0 = __uint_as_float(p0.u & 0xFFFF0000u);
            float fa1 = __uint_as_float(p1.u << 16), fb1 = __uint_as_float(p1.u & 0xFFFF0000u);
            float fa2 = __uint_as_float(p2.u << 16), fb2 = __uint_as_float(p2.u & 0xFFFF0000u);
            float fa3 = __uint_as_float(p3.u << 16), fb3 = __uint_as_float(p3.u & 0xFFFF0000u);
            ts0 = fmaf(fa0, fa0, fmaf(fb0, fb0, ts0));
            ts1 = fmaf(fa1, fa1, fmaf(fb1, fb1, ts1));
            ts2 = fmaf(fa2, fa2, fmaf(fb2, fb2, ts2));
            ts3 = fmaf(fa3, fa3, fmaf(fb3, fb3, ts3));
            uint4 pk;
            pk.x = p0.u; pk.y = p1.u; pk.z = p2.u; pk.w = p3.u;
            *(uint4*)(&Blb[buf * (16 * BLROW) + pair * BLROW + nq * 4]) = pk;
        }
    };

    auto body = [&](int ks, float4* rload, float4* rcons) {
        if (ks < 30) ldtile(ks + 2, rload);     // 2-deep prefetch, stays in flight across barriers

        short8 af0 = *(const short8*)(ap + ((size_t)(ks * 4 + g) * 64 + mhalf * 32 + 0 * 16 + (l & 15)) * 8);
        short8 af1 = *(const short8*)(ap + ((size_t)(ks * 4 + g) * 64 + mhalf * 32 + 1 * 16 + (l & 15)) * 8);

        const unsigned* Bc = Blb + (ks & 1) * (16 * BLROW);
        #pragma unroll
        for (int nf = 0; nf < 4; ++nf) {
            int nn = nnb + nf * 16;
            union { unsigned u[4]; short8 s; } bu;
            bu.u[0] = Bc[(g * 4 + 0) * BLROW + nn];
            bu.u[1] = Bc[(g * 4 + 1) * BLROW + nn];
            bu.u[2] = Bc[(g * 4 + 2) * BLROW + nn];
            bu.u[3] = Bc[(g * 4 + 3) * BLROW + nn];
            accf[0][nf] = __builtin_amdgcn_mfma_f32_16x16x32_bf16(af0, bu.s, accf[0][nf], 0, 0, 0);
            accf[1][nf] = __builtin_amdgcn_mfma_f32_16x16x32_bf16(af1, bu.s, accf[1][nf], 0, 0, 0);
        }

        if (ks < 31) cvt_write((ks + 1) & 1, rcons);
    };

    float4 r0[4], r1[4];
    ldtile(0, r0);
    ldtile(1, r1);
    cvt_write(0, r0);

    #pragma unroll 1
    for (int ks = 0; ks < 32; ks += 2) {
        TILE_BARRIER();
        body(ks, r0, r1);       // loads ks+2 -> r0, consumes r1 (tile ks+1)
        TILE_BARRIER();
        body(ks + 1, r1, r0);   // loads ks+3 -> r1, consumes r0 (tile ks+2)
    }

    // tesq reduce across the 8 pair-groups
    __syncthreads();
    tsp[rp * 256 + nq * 4 + 0] = ts0;
    tsp[rp * 256 + nq * 4 + 1] = ts1;
    tsp[rp * 256 + nq * 4 + 2] = ts2;
    tsp[rp * 256 + nq * 4 + 3] = ts3;
    __syncthreads();
    if (t < 64) {
        float4 s = make_float4(0.f, 0.f, 0.f, 0.f);
        #pragma unroll
        for (int r = 0; r < 8; ++r) {
            float4 v = *(const float4*)(&tsp[r * 256 + t * 4]);
            s.x += v.x; s.y += v.y; s.z += v.z; s.w += v.w;
        }
        *(float4*)(&tsf[t * 4]) = s;
        if (nbase + t * 4 < N)
            *(float4*)(ws + OFF_TESQ + nbase + t * 4) = s;
    }
    __syncthreads();

    // epilogue: keys + per-wave range
    unsigned* uws = (unsigned*)ws;
    unsigned kmin = 0xFFFFFFFFu, kmax = 0u;
    #pragma unroll
    for (int mf = 0; mf < 2; ++mf) {
        #pragma unroll
        for (int nf = 0; nf < 4; ++nf) {
            int nloc = nnb + nf * 16;
            int nabs = nbase + nloc;
            #pragma unroll
            for (int r = 0; r < 4; ++r) {
                int c = mhalf * 32 + mf * 16 + (l >> 4) * 4 + r;   // C/D row map (m89)
                if (c < 50 && nabs < N) {
                    unsigned u = keyu(accf[mf][nf][r], tsf[nloc]);
                    uws[(size_t)c * N + nabs] = u;
                    kmin = min(kmin, u);
                    kmax = max(kmax, u);
                }
            }
        }
    }
    #pragma unroll
    for (int off = 32; off > 0; off >>= 1) {
        kmin = min(kmin, (unsigned)__shfl_down((int)kmin, off, 64));
        kmax = max(kmax, (unsigned)__shfl_down((int)kmax, off, 64));
    }
    if (l == 0) {
        int slot = blockIdx.x * 8 + w;
        ((unsigned*)(ws + OFF_RANGE))[2 * slot]     = kmin;
        ((unsigned*)(ws + OFF_RANGE))[2 * slot + 1] = kmax;
    }
}

// ---------------- Kpred: [orig_pred | y_pred] = X @ W8 + bias -----------------
__global__ __launch_bounds__(256) void kpred(
    const float* __restrict__ X, const float* __restrict__ hxb,
    const float* __restrict__ ws, float* __restrict__ out)
{
    int t = threadIdx.x;
    int lane = t & 63, w = t >> 6;
    int r = blockIdx.x * 4 + w;
    const float* xr = X + (size_t)r * D;
    const float* w8 = ws + OFF_W8;

    float acc[8];
    #pragma unroll
    for (int j = 0; j < 8; ++j) acc[j] = 0.f;
    #pragma unroll
    for (int i = 0; i < 16; ++i) {
        int d = i * 64 + lane;
        float x = xr[d];
        float4 lo = *(const float4*)(w8 + (size_t)d * 8);
        float4 hi = *(const float4*)(w8 + (size_t)d * 8 + 4);
        acc[0] = fmaf(x, lo.x, acc[0]);
        acc[1] = fmaf(x, lo.y, acc[1]);
        acc[2] = fmaf(x, lo.z, acc[2]);
        acc[3] = fmaf(x, lo.w, acc[3]);
        acc[4] = fmaf(x, hi.x, acc[4]);
        acc[5] = fmaf(x, hi.y, acc[5]);
        acc[6] = fmaf(x, hi.z, acc[6]);
        acc[7] = fmaf(x, hi.w, acc[7]);
    }
    #pragma unroll
    for (int j = 0; j < 8; ++j) {
        float v = acc[j];
        #pragma unroll
        for (int off = 32; off > 0; off >>= 1) v += __shfl_down(v, off, 64);
        if (lane == 0) {
            float b = hxb[j & 3];
            if (j < 4) out[(size_t)r * CLS + j] = v + b;
            else       out[16384 + (size_t)r * CLS + (j - 4)] = v + b;
        }
    }
}

// ---------------- K4: GR preamble + top-k from u keys + fused L_sparse_1 ------
__global__ __launch_bounds__(1024) void k4_select(
    const float* __restrict__ ws, float* __restrict__ wsw,
    float* __restrict__ out, const int* __restrict__ topk)
{
    int c = blockIdx.x, t = threadIdx.x;
    int lane = t & 63, wid = t >> 6;
    const unsigned* uarr = (const unsigned*)ws + (size_t)c * N;
    const float* tesq = ws + OFF_TESQ;

    __shared__ unsigned hist[4096];
    __shared__ unsigned wsum[16], woff[16];
    __shared__ unsigned wmn[16], wmx[16];
    __shared__ unsigned sh_ulo, sh_uhi;
    __shared__ unsigned sh_bin; __shared__ int sh_rem;
    __shared__ int cnt;
    __shared__ unsigned cand_u[CAP];
    __shared__ int      cand_i[CAP];
    __shared__ float fred[16];

    // preamble: global key range from wave slots
    {
        const unsigned* rg = (const unsigned*)(ws + OFF_RANGE);
        unsigned mn = 0xFFFFFFFFu, mx = 0u;
        for (int i = t; i < NSLOT; i += 1024) {
            mn = min(mn, rg[2 * i]);
            mx = max(mx, rg[2 * i + 1]);
        }
        #pragma unroll
        for (int off = 32; off > 0; off >>= 1) {
            mn = min(mn, (unsigned)__shfl_down((int)mn, off, 64));
            mx = max(mx, (unsigned)__shfl_down((int)mx, off, 64));
        }
        if (lane == 0) { wmn[wid] = mn; wmx[wid] = mx; }
        __syncthreads();
        if (t == 0) {
            unsigned m0 = 0xFFFFFFFFu, m1 = 0u;
            for (int w = 0; w < 16; ++w) { m0 = min(m0, wmn[w]); m1 = max(m1, wmx[w]); }
            sh_ulo = m0; sh_uhi = m1;
        }
        __syncthreads();
    }
    unsigned ubase = sh_ulo;
    unsigned ulo = sh_ulo, uhi = sh_uhi;
    int rem = *topk;
    unsigned long long width = (unsigned long long)(uhi - ulo) + 1ull;

    // pass 1: histogram over 4096 linear bins
    for (int i = t; i < 4096; i += 1024) hist[i] = 0u;
    __syncthreads();
    for (int n = t; n < N; n += 1024) {
        unsigned u = uarr[n];
        unsigned bin = (unsigned)(((unsigned long long)(u - ubase) * 4096ull) / width);
        atomicAdd(&hist[bin], 1u);
    }
    __syncthreads();
    {
        unsigned b0 = (unsigned)t * 4u;
        unsigned h0 = hist[b0], h1 = hist[b0 + 1], h2 = hist[b0 + 2], h3 = hist[b0 + 3];
        unsigned s4 = h0 + h1 + h2 + h3;
        unsigned x = s4;
        #pragma unroll
        for (int off = 1; off < 64; off <<= 1) {
            unsigned y = (unsigned)__shfl_up((int)x, off, 64);
            if (lane >= off) x += y;
        }
        if (lane == 63) wsum[wid] = x;
        __syncthreads();
        if (t == 0) {
            unsigned run = 0;
            for (int w = 0; w < 16; ++w) { woff[w] = run; run += wsum[w]; }
        }
        __syncthreads();
        unsigned cumBefore = woff[wid] + x - s4;
        unsigned remu = (unsigned)rem;
        if (cumBefore < remu && remu <= cumBefore + s4) {
            unsigned cum = cumBefore, bin = b0, r2 = 1;
            unsigned hh[4] = {h0, h1, h2, h3};
            #pragma unroll
            for (int j = 0; j < 4; ++j) {
                if (cum + hh[j] >= remu) { bin = b0 + j; r2 = remu - cum; break; }
                cum += hh[j];
            }
            sh_bin = bin; sh_rem = (int)r2;
        }
        __syncthreads();
        unsigned b = sh_bin;
        rem = sh_rem;
        ulo = ubase + (unsigned)(((unsigned long long)b * width + 4095ull) / 4096ull);
        uhi = ubase + (unsigned)((((unsigned long long)(b + 1) * width + 4095ull) / 4096ull) - 1ull);
        __syncthreads();
    }

    // final: sum recovered dots below cutoff bin; collect cutoff-bin candidates
    if (t == 0) cnt = 0;
    __syncthreads();
    float lsum = 0.f;
    for (int n = t; n < N; n += 1024) {
        unsigned u = uarr[n];
        if (u < ulo) {
            lsum += 0.5f * (tesq[n] - unmapf(u));
        } else if (u <= uhi) {
            int s = atomicAdd(&cnt, 1);
            if (s < CAP) { cand_u[s] = u; cand_i[s] = n; }
        }
    }
    __syncthreads();
    int cc = cnt < CAP ? cnt : CAP;
    for (int ci = t; ci < cc; ci += 1024) {
        unsigned ui = cand_u[ci]; int ii = cand_i[ci];
        int rank = 0;
        for (int j = 0; j < cc; ++j) {
            unsigned uj = cand_u[j];
            rank += (uj < ui || (uj == ui && cand_i[j] < ii)) ? 1 : 0;
        }
        if (rank < rem) lsum += 0.5f * (tesq[ii] - unmapf(ui));
    }
    #pragma unroll
    for (int off = 32; off > 0; off >>= 1) lsum += __shfl_down(lsum, off, 64);
    if (lane == 0) fred[wid] = lsum;
    __syncthreads();
    if (t == 0) {
        float tot = 0.f;
        for (int w = 0; w < 16; ++w) tot += fred[w];
        wsw[OFF_SUMS + c] = tot;
        __threadfence();
        unsigned done = atomicAdd((unsigned*)(wsw + OFF_CNT), 1u);
        if (done == C - 1) {
            float s = 0.f;
            for (int i = 0; i < C; ++i) s += atomicAdd(&wsw[OFF_SUMS + i], 0.0f);
            out[32768] = s / (float)((*topk) * C);
        }
    }
}

extern "C" void kernel_launch(void* const* d_in, const int* in_sizes, int n_in,
                              void* d_out, int out_size, void* d_ws, size_t ws_size,
                              hipStream_t stream) {
    (void)in_sizes; (void)n_in; (void)out_size; (void)ws_size;
    const float* concept = (const float*)d_in[0];
    const float* te      = (const float*)d_in[1];
    const float* X       = (const float*)d_in[2];
    const float* hxw     = (const float*)d_in[3];
    const float* hxb     = (const float*)d_in[4];
    const int*   topk    = (const int*)d_in[5];
    float* out = (float*)d_out;
    float* ws  = (float*)d_ws;

    kprep<<<dim3(KParts + 1), dim3(256), 0, stream>>>(concept, hxw, ws);
    kgemm<<<dim3(NBLK + 1), dim3(512), 0, stream>>>(concept, te, hxw, ws, out);
    kpred<<<dim3(B / 4), dim3(256), 0, stream>>>(X, hxb, ws, out);
    k4_select<<<dim3(C), dim3(1024), 0, stream>>>(ws, ws, out, topk);
}